// Round 10
// baseline (74.644 us; speedup 1.0000x reference)
//
#include <hip/hip_runtime.h>

#define CI 32
#define CO 32
#define PD 64
#define QDIM 1024
#define M_TOTAL (32*4096)
#define TILE_M 128                 // per WG (4 waves x 32 rows)
#define NBLK (M_TOTAL/TILE_M)      // 1024 WGs -> 4 per CU
#define WG_THREADS 256

typedef float  f32x4  __attribute__((ext_vector_type(4)));
typedef float  f32x16 __attribute__((ext_vector_type(16)));
typedef __bf16 bf16x4 __attribute__((ext_vector_type(4)));
typedef __bf16 bf16x8 __attribute__((ext_vector_type(8)));

#define XL_STRIDE 129   // Xl[i][m]: reads stride-1 (free); writes <=2-way
#define OL_STRIDE 33    // Ol[m][o]: writes <=2-way; b32 reads free

// ---- one-time: Wk [64][1024] f32 -> wsT [1024][64] bf16 (64 WGs, ~2us) ----
__global__ __launch_bounds__(256)
void wk_transpose_kernel(const float* __restrict__ Wk, __bf16* __restrict__ wsT)
{
    __shared__ float tile[64][17];
    const int q0 = blockIdx.x * 16;
    const int t  = threadIdx.x;
    const int k  = t >> 2;          // 0..63
    const int c4 = (t & 3) * 4;     // 0,4,8,12
    f32x4 v = *(const f32x4*)(Wk + (size_t)k * QDIM + q0 + c4);
    tile[k][c4+0] = v[0]; tile[k][c4+1] = v[1]; tile[k][c4+2] = v[2]; tile[k][c4+3] = v[3];
    __syncthreads();
    const int q  = t >> 4;          // 0..15
    const int k0 = (t & 15) * 4;    // 0..60
    bf16x4 o;
#pragma unroll
    for (int j = 0; j < 4; ++j) o[j] = (__bf16)tile[k0 + j][q];
    *(bf16x4*)(wsT + (size_t)(q0 + q) * PD + k0) = o;
}

// Swapped-operand scheme: D = Wk^T (A, 32q x 16k) * P^T (B, 16k x 32m).
// Lane owns output ROW m (= l&31); regs own all 32 o's per i. X becomes a
// lane-scalar LDS read; the i-reduction is register-local; NO barriers in
// the i-loop; waves fully independent. A streams from L2-resident wsT.
__global__ __launch_bounds__(WG_THREADS, 4)
void cond_dense_kernel(const float* __restrict__ Xg, const float* __restrict__ Pg,
                       const __bf16* __restrict__ wsT, float* __restrict__ outg)
{
    __shared__ union ShU {
        __bf16 p[TILE_M * PD];          // 16384 B: P-tile, 16B-granule XOR-swizzled
        float  o[TILE_M * OL_STRIDE];   // 16896 B: output staging (after i-loop)
    } U;
    __shared__ float Xl[CI * XL_STRIDE];  // 16512 B: X transposed [i][m]

    const int tid = threadIdx.x;
    const int l   = tid & 63;
    const int w   = tid >> 6;       // wave 0..3 -> rows w*32..w*32+31
    const int l31 = l & 31;
    const int hi  = l >> 5;         // 0/1: k-half within a K=16 MFMA
    const int m   = w * 32 + l31;   // this lane's output row (B/C col)

    const int tile0 = blockIdx.x * TILE_M;

    // ---- stage: P[128][64] -> bf16 swizzled; X[128][32] -> Xl[i][m] ----
    {
        const float* Pb = Pg + (size_t)tile0 * PD;
        const int prow = tid >> 4;       // 0..15 (+16s)
        const int pch  = tid & 15;       // f32x4 chunk within 64-f32 row
#pragma unroll
        for (int s = 0; s < 8; ++s) {
            const int r = prow + s * 16;
            f32x4 v = *(const f32x4*)(Pb + (size_t)r * PD + pch * 4);
            bf16x4 bv;
#pragma unroll
            for (int j = 0; j < 4; ++j) bv[j] = (__bf16)v[j];
            char* dst = (char*)U.p + r * 128
                      + ((((pch >> 1) ^ (r & 7)) << 4) | ((pch & 1) * 8));
            *(bf16x4*)dst = bv;
        }
        const float* Xb = Xg + (size_t)tile0 * CI;
        const int xrow = tid >> 3;       // 0..31 (+32s)
        const int xch  = tid & 7;        // f32x4 chunk within 32-f32 row
#pragma unroll
        for (int s = 0; s < 4; ++s) {
            const int r = xrow + s * 32;
            f32x4 v = *(const f32x4*)(Xb + (size_t)r * CI + xch * 4);
#pragma unroll
            for (int j = 0; j < 4; ++j)
                Xl[(xch * 4 + j) * XL_STRIDE + r] = v[j];
        }
    }
    __syncthreads();

    // ---- B fragments: P^T for this wave's 32 rows; 16 VGPR, loop-invariant ----
    // B[k][m]: lane col m=l31, k = kq*16 + hi*8 + j  -> granule 2kq+hi, swizzled
    bf16x8 bfr[4];
#pragma unroll
    for (int kq = 0; kq < 4; ++kq) {
        const int g = ((kq * 2 + hi) ^ (m & 7)) << 4;
        bfr[kq] = *(const bf16x8*)((const char*)U.p + m * 128 + g);
    }

    // ---- i-loop: A from global wsT (L2-broadcast), relu+fmac in-register ----
    f32x16 oacc = {};
    const __bf16* ap = wsT + (size_t)l31 * PD + hi * 8;  // row q = i*32+l31
#pragma unroll 2
    for (int i = 0; i < CI; ++i) {
        bf16x8 a0 = *(const bf16x8*)(ap +  0);   // kq=0: k = hi*8+j
        bf16x8 a1 = *(const bf16x8*)(ap + 16);   // kq=1
        bf16x8 a2 = *(const bf16x8*)(ap + 32);   // kq=2
        bf16x8 a3 = *(const bf16x8*)(ap + 48);   // kq=3
        ap += 32 * PD;                           // next i: q += 32
        f32x16 acc = {};
        acc = __builtin_amdgcn_mfma_f32_32x32x16_bf16(a0, bfr[0], acc, 0, 0, 0);
        acc = __builtin_amdgcn_mfma_f32_32x32x16_bf16(a1, bfr[1], acc, 0, 0, 0);
        acc = __builtin_amdgcn_mfma_f32_32x32x16_bf16(a2, bfr[2], acc, 0, 0, 0);
        acc = __builtin_amdgcn_mfma_f32_32x32x16_bf16(a3, bfr[3], acc, 0, 0, 0);
        const float x = Xl[i * XL_STRIDE + m];   // lane-scalar, conflict-free
#pragma unroll
        for (int r = 0; r < 16; ++r)
            oacc[r] += fmaxf(acc[r], 0.0f) * x;  // i-sum stays in-register
    }

    __syncthreads();   // all waves done reading U.p -> reuse as Ol

    // ---- stage output: lane holds row m, o = (r&3)+8*(r>>2)+4*hi ----
#pragma unroll
    for (int r = 0; r < 16; ++r) {
        const int o = (r & 3) + 8 * (r >> 2) + 4 * hi;
        U.o[m * OL_STRIDE + o] = oacc[r];
    }
    __syncthreads();

    // ---- coalesced store: 4 x f32x4 per thread, full 128B lines ----
    {
        const int srow = tid >> 3, sch = (tid & 7) * 4;
#pragma unroll
        for (int s = 0; s < 4; ++s) {
            const int r = srow + s * 32;
            f32x4 v;
#pragma unroll
            for (int j = 0; j < 4; ++j) v[j] = U.o[r * OL_STRIDE + sch + j];
            *(f32x4*)(outg + (size_t)(tile0 + r) * CO + sch) = v;
        }
    }
}

extern "C" void kernel_launch(void* const* d_in, const int* in_sizes, int n_in,
                              void* d_out, int out_size, void* d_ws, size_t ws_size,
                              hipStream_t stream)
{
    const float* X  = (const float*)d_in[0];
    const float* P  = (const float*)d_in[1];
    const float* Wk = (const float*)d_in[2];
    float* out = (float*)d_out;
    __bf16* wsT = (__bf16*)d_ws;   // 1024*64*2 = 128 KB

    wk_transpose_kernel<<<dim3(QDIM / 16), dim3(256), 0, stream>>>(Wk, wsT);
    cond_dense_kernel<<<dim3(NBLK), dim3(WG_THREADS), 0, stream>>>(X, P, wsT, out);
}

// Round 11
// 48.275 us; speedup vs baseline: 1.5462x; 1.5462x over previous
//
#include <hip/hip_runtime.h>

#define CI 32
#define CO 32
#define PD 64
#define QDIM 1024
#define M_TOTAL (32*4096)
#define TILE_M 256                 // per WG: 4 waves x 2 row-blocks x 32 rows
#define NBLK (M_TOTAL/TILE_M)      // 512 WGs -> exactly 2 per CU, 1 generation
#define WG_THREADS 256

typedef float  f32x4  __attribute__((ext_vector_type(4)));
typedef float  f32x16 __attribute__((ext_vector_type(16)));
typedef __bf16 bf16x4 __attribute__((ext_vector_type(4)));
typedef __bf16 bf16x8 __attribute__((ext_vector_type(8)));

#define XLS 257    // Xl[i][m]: bank (i+m)%32 -> conflict-free lane-scalar reads
#define OLS 33     // Ol[m][o]: <=2-way on writes

// ---- one-time: Wk [64][1024] f32 -> wsT [1024][64] bf16 (64 WGs) ----
__global__ __launch_bounds__(256)
void wk_transpose_kernel(const float* __restrict__ Wk, __bf16* __restrict__ wsT)
{
    __shared__ float tile[64][17];
    const int q0 = blockIdx.x * 16;
    const int t  = threadIdx.x;
    const int k  = t >> 2;
    const int c4 = (t & 3) * 4;
    f32x4 v = *(const f32x4*)(Wk + (size_t)k * QDIM + q0 + c4);
    tile[k][c4+0] = v[0]; tile[k][c4+1] = v[1]; tile[k][c4+2] = v[2]; tile[k][c4+3] = v[3];
    __syncthreads();
    const int q  = t >> 4;
    const int k0 = (t & 15) * 4;
    bf16x4 o;
#pragma unroll
    for (int j = 0; j < 4; ++j) o[j] = (__bf16)tile[k0 + j][q];
    *(bf16x4*)(wsT + (size_t)(q0 + q) * PD + k0) = o;
}

// Swapped-operand scheme, R=2: lane owns rows mlo/mhi; X lane-local; i-sum
// in-register; ZERO barriers in the i-loop. A (Wk^T) streams from L2-resident
// wsT, double-buffered 2-deep, each load shared by both row-blocks.
// launch_bounds(256,2): 256-VGPR budget so a0/a1 buffers stay resident
// (VGPR=52 in R10 = allocator gave A-frags no room -> serialized loads).
__global__ __launch_bounds__(WG_THREADS, 2)
void cond_dense_kernel(const float* __restrict__ Xg, const float* __restrict__ Pg,
                       const __bf16* __restrict__ wsT, float* __restrict__ outg)
{
    __shared__ union {
        __bf16 p[TILE_M * PD];        // 32768 B: P-tile, 16B-granule XOR-swizzled
        float  o[TILE_M * OLS];       // 33792 B: output staging (after i-loop)
    } U;
    __shared__ float Xl[CI * XLS];    // 32896 B: X transposed [i][m]

    const int tid = threadIdx.x;
    const int l   = tid & 63;
    const int w   = tid >> 6;       // wave 0..3 -> rows w*64 .. w*64+63
    const int l31 = l & 31;
    const int hi  = l >> 5;         // k-half within K=16 MFMA
    const int mlo = w * 64 + l31;
    const int mhi = mlo + 32;
    const int tile0 = blockIdx.x * TILE_M;

    // ---- stage: P[256][64]->bf16 swizzled LDS; X[256][32]->Xl[i][m] ----
    {
        const float* Pb = Pg + (size_t)tile0 * PD;
        const int pr = tid >> 4, pch = tid & 15;
#pragma unroll
        for (int s = 0; s < 16; ++s) {
            const int r = pr + s * 16;
            f32x4 v = *(const f32x4*)(Pb + (size_t)r * PD + pch * 4);
            bf16x4 bv;
#pragma unroll
            for (int j = 0; j < 4; ++j) bv[j] = (__bf16)v[j];
            char* dst = (char*)U.p + r * 128
                      + ((((pch >> 1) ^ (r & 7)) << 4) | ((pch & 1) * 8));
            *(bf16x4*)dst = bv;
        }
        const float* Xb = Xg + (size_t)tile0 * CI;
        const int xr = tid >> 3, xch = tid & 7;
#pragma unroll
        for (int s = 0; s < 8; ++s) {
            const int r = xr + s * 32;
            f32x4 v = *(const f32x4*)(Xb + (size_t)r * CI + xch * 4);
#pragma unroll
            for (int j = 0; j < 4; ++j)
                Xl[(xch * 4 + j) * XLS + r] = v[j];
        }
    }
    __syncthreads();

    // ---- B fragments (P^T) for both row-blocks: 32 VGPR, loop-invariant ----
    bf16x8 bfA[4], bfB[4];
#pragma unroll
    for (int kq = 0; kq < 4; ++kq) {
        const int g = ((kq * 2 + hi) ^ (mlo & 7)) << 4;   // mhi&7 == mlo&7
        bfA[kq] = *(const bf16x8*)((const char*)U.p + mlo * 128 + g);
        bfB[kq] = *(const bf16x8*)((const char*)U.p + mhi * 128 + g);
    }

    f32x16 oA = {}, oB = {};
    const __bf16* abase = wsT + (size_t)l31 * PD + hi * 8;

    bf16x8 a0[4], a1[4];   // 2-deep A double-buffer (static roles, even/odd i)
    auto aload = [&](int i, bf16x8* buf) {
        const __bf16* ap = abase + (size_t)i * (32 * PD);
        buf[0] = *(const bf16x8*)(ap);
        buf[1] = *(const bf16x8*)(ap + 16);
        buf[2] = *(const bf16x8*)(ap + 32);
        buf[3] = *(const bf16x8*)(ap + 48);
    };
    auto step = [&](const bf16x8* a, float xl, float xh) {
        f32x16 cA = {}, cB = {};
#pragma unroll
        for (int kq = 0; kq < 4; ++kq) {     // A shared by both blocks (amortize)
            cA = __builtin_amdgcn_mfma_f32_32x32x16_bf16(a[kq], bfA[kq], cA, 0, 0, 0);
            cB = __builtin_amdgcn_mfma_f32_32x32x16_bf16(a[kq], bfB[kq], cB, 0, 0, 0);
        }
#pragma unroll
        for (int r = 0; r < 16; ++r) {
            oA[r] += fmaxf(cA[r], 0.0f) * xl;
            oB[r] += fmaxf(cB[r], 0.0f) * xh;
        }
    };

    aload(0, a0);
    aload(1, a1);
    for (int ii = 0; ii < 16; ++ii) {
        const int i0 = 2 * ii, i1 = i0 + 1;
        const float x0l = Xl[i0 * XLS + mlo], x0h = Xl[i0 * XLS + mhi];
        const float x1l = Xl[i1 * XLS + mlo], x1h = Xl[i1 * XLS + mhi];
        step(a0, x0l, x0h);                 // consume even buffer
        if (ii < 15) aload(i0 + 2, a0);     // reload: full next-step compute covers latency
        step(a1, x1l, x1h);                 // consume odd buffer
        if (ii < 15) aload(i1 + 2, a1);
    }

    __syncthreads();   // all waves done reading U.p -> reuse as Ol

    // ---- stage output: lane row m, o = (r&3)+8*(r>>2)+4*hi ----
#pragma unroll
    for (int r = 0; r < 16; ++r) {
        const int o = (r & 3) + 8 * (r >> 2) + 4 * hi;
        U.o[mlo * OLS + o] = oA[r];
        U.o[mhi * OLS + o] = oB[r];
    }
    __syncthreads();

    // ---- coalesced store: 8 x f32x4 per thread, full 128B lines ----
    {
        const int sr = tid >> 3, sch = (tid & 7) * 4;
#pragma unroll
        for (int s = 0; s < 8; ++s) {
            const int r = sr + s * 32;
            f32x4 v;
#pragma unroll
            for (int j = 0; j < 4; ++j) v[j] = U.o[r * OLS + sch + j];
            *(f32x4*)(outg + (size_t)(tile0 + r) * CO + sch) = v;
        }
    }
}

extern "C" void kernel_launch(void* const* d_in, const int* in_sizes, int n_in,
                              void* d_out, int out_size, void* d_ws, size_t ws_size,
                              hipStream_t stream)
{
    const float* X  = (const float*)d_in[0];
    const float* P  = (const float*)d_in[1];
    const float* Wk = (const float*)d_in[2];
    float* out = (float*)d_out;
    __bf16* wsT = (__bf16*)d_ws;   // 1024*64*2 = 128 KB

    wk_transpose_kernel<<<dim3(QDIM / 16), dim3(256), 0, stream>>>(Wk, wsT);
    cond_dense_kernel<<<dim3(NBLK), dim3(WG_THREADS), 0, stream>>>(X, P, wsT, out);
}

// Round 12
// 38.399 us; speedup vs baseline: 1.9439x; 1.2572x over previous
//
#include <hip/hip_runtime.h>

#define CI 32
#define CO 32
#define PD 64
#define QDIM 1024
#define M_TOTAL (32*4096)
#define TILE_M 256                 // per WG: 4 waves x 2 row-blocks x 32 rows
#define NBLK (M_TOTAL/TILE_M)      // 512 WGs -> 2 per CU, 1 generation
#define WG_THREADS 256

typedef float  f32x4  __attribute__((ext_vector_type(4)));
typedef float  f32x16 __attribute__((ext_vector_type(16)));
typedef __bf16 bf16x4 __attribute__((ext_vector_type(4)));
typedef __bf16 bf16x8 __attribute__((ext_vector_type(8)));

#define XLS 257    // Xl[i][m]: bank (i+m)%32 -> conflict-free lane-scalar reads
#define OLS 33     // Ol[m][o]: <=2-way on writes

// ---- one-time: Wk [64][1024] f32 -> wsF, the A-panel layout ----
// wsF elem idx = (q>>5)*2048 + (k>>3)*256 + (q&31)*8 + (k&7)  [bf16]
// so that lane (l31,hi), chunk c of step i reads contiguous:
//   wsF + i*2048 + (2c+hi)*256 + l31*8   (wave-contiguous 1024 B)
__global__ __launch_bounds__(256)
void wk_pack_kernel(const float* __restrict__ Wk, __bf16* __restrict__ wsF)
{
    __shared__ float tile[64][33];
    const int q0 = blockIdx.x * 32;
    const int t  = threadIdx.x;
#pragma unroll
    for (int s = 0; s < 2; ++s) {
        const int idx = t + s * 256;
        const int k = idx >> 3, ch = idx & 7;
        f32x4 v = *(const f32x4*)(Wk + (size_t)k * QDIM + q0 + ch * 4);
        tile[k][ch*4+0] = v[0]; tile[k][ch*4+1] = v[1];
        tile[k][ch*4+2] = v[2]; tile[k][ch*4+3] = v[3];
    }
    __syncthreads();
    const int qq = t >> 3;          // 0..31
    const int g  = t & 7;           // k-octet
    bf16x8 o;
#pragma unroll
    for (int j = 0; j < 8; ++j) o[j] = (__bf16)tile[g*8 + j][qq];
    *(bf16x8*)(wsF + (size_t)blockIdx.x * 2048 + g * 256 + qq * 8) = o;
}

// Swapped-operand scheme, R=2 (R11) + COALESCED A-loads from wsF.
// R11 lesson: wsT A-loads had 128B lane stride -> 32 lines/instr, 16B/64B
// sector payload; per-CU sector rate was the wall. wsF makes each A-load
// one contiguous 1024B wave transaction.
__global__ __launch_bounds__(WG_THREADS, 2)
void cond_dense_kernel(const float* __restrict__ Xg, const float* __restrict__ Pg,
                       const __bf16* __restrict__ wsF, float* __restrict__ outg)
{
    __shared__ union {
        __bf16 p[TILE_M * PD];        // 32768 B: P-tile, 16B-granule XOR-swizzled
        float  o[TILE_M * OLS];       // 33792 B: output staging (after i-loop)
    } U;
    __shared__ float Xl[CI * XLS];    // 32896 B: X transposed [i][m]

    const int tid = threadIdx.x;
    const int l   = tid & 63;
    const int w   = tid >> 6;       // wave 0..3 -> rows w*64 .. w*64+63
    const int l31 = l & 31;
    const int hi  = l >> 5;         // k-half within K=16 MFMA
    const int mlo = w * 64 + l31;
    const int mhi = mlo + 32;
    const int tile0 = blockIdx.x * TILE_M;

    // ---- stage: P[256][64]->bf16 swizzled LDS; X[256][32]->Xl[i][m] ----
    {
        const float* Pb = Pg + (size_t)tile0 * PD;
        const int pr = tid >> 4, pch = tid & 15;
#pragma unroll
        for (int s = 0; s < 16; ++s) {
            const int r = pr + s * 16;
            f32x4 v = *(const f32x4*)(Pb + (size_t)r * PD + pch * 4);
            bf16x4 bv;
#pragma unroll
            for (int j = 0; j < 4; ++j) bv[j] = (__bf16)v[j];
            char* dst = (char*)U.p + r * 128
                      + ((((pch >> 1) ^ (r & 7)) << 4) | ((pch & 1) * 8));
            *(bf16x4*)dst = bv;
        }
        const float* Xb = Xg + (size_t)tile0 * CI;
        const int xr = tid >> 3, xch = tid & 7;
#pragma unroll
        for (int s = 0; s < 8; ++s) {
            const int r = xr + s * 32;
            f32x4 v = *(const f32x4*)(Xb + (size_t)r * CI + xch * 4);
#pragma unroll
            for (int j = 0; j < 4; ++j)
                Xl[(xch * 4 + j) * XLS + r] = v[j];
        }
    }
    __syncthreads();

    // ---- B fragments (P^T) for both row-blocks: 32 VGPR, loop-invariant ----
    bf16x8 bfA[4], bfB[4];
#pragma unroll
    for (int kq = 0; kq < 4; ++kq) {
        const int g = ((kq * 2 + hi) ^ (mlo & 7)) << 4;   // mhi&7 == mlo&7
        bfA[kq] = *(const bf16x8*)((const char*)U.p + mlo * 128 + g);
        bfB[kq] = *(const bf16x8*)((const char*)U.p + mhi * 128 + g);
    }

    f32x16 oA = {}, oB = {};
    // lane base into the per-i A-panel: chunk c at +(2c+hi)*256 elements
    const __bf16* abase = wsF + (size_t)hi * 256 + (size_t)l31 * 8;

    bf16x8 a0[4], a1[4];   // 2-deep A double-buffer (static roles, even/odd i)
    auto aload = [&](int i, bf16x8* buf) {
        const __bf16* ap = abase + (size_t)i * 2048;
        buf[0] = *(const bf16x8*)(ap);          // c=0
        buf[1] = *(const bf16x8*)(ap +  512);   // c=1
        buf[2] = *(const bf16x8*)(ap + 1024);   // c=2
        buf[3] = *(const bf16x8*)(ap + 1536);   // c=3
    };
    auto step = [&](const bf16x8* a, float xl, float xh) {
        f32x16 cA = {}, cB = {};
#pragma unroll
        for (int kq = 0; kq < 4; ++kq) {     // A shared by both blocks
            cA = __builtin_amdgcn_mfma_f32_32x32x16_bf16(a[kq], bfA[kq], cA, 0, 0, 0);
            cB = __builtin_amdgcn_mfma_f32_32x32x16_bf16(a[kq], bfB[kq], cB, 0, 0, 0);
        }
#pragma unroll
        for (int r = 0; r < 16; ++r) {
            oA[r] += fmaxf(cA[r], 0.0f) * xl;
            oB[r] += fmaxf(cB[r], 0.0f) * xh;
        }
    };

    aload(0, a0);
    aload(1, a1);
    for (int ii = 0; ii < 16; ++ii) {
        const int i0 = 2 * ii, i1 = i0 + 1;
        const float x0l = Xl[i0 * XLS + mlo], x0h = Xl[i0 * XLS + mhi];
        const float x1l = Xl[i1 * XLS + mlo], x1h = Xl[i1 * XLS + mhi];
        step(a0, x0l, x0h);                 // consume even buffer
        if (ii < 15) aload(i0 + 2, a0);
        step(a1, x1l, x1h);                 // consume odd buffer
        if (ii < 15) aload(i1 + 2, a1);
    }

    __syncthreads();   // all waves done reading U.p -> reuse as Ol

    // ---- stage output: lane row m, o = (r&3)+8*(r>>2)+4*hi ----
#pragma unroll
    for (int r = 0; r < 16; ++r) {
        const int o = (r & 3) + 8 * (r >> 2) + 4 * hi;
        U.o[mlo * OLS + o] = oA[r];
        U.o[mhi * OLS + o] = oB[r];
    }
    __syncthreads();

    // ---- coalesced store: 8 x f32x4 per thread, full 128B lines ----
    {
        const int sr = tid >> 3, sch = (tid & 7) * 4;
#pragma unroll
        for (int s = 0; s < 8; ++s) {
            const int r = sr + s * 32;
            f32x4 v;
#pragma unroll
            for (int j = 0; j < 4; ++j) v[j] = U.o[r * OLS + sch + j];
            *(f32x4*)(outg + (size_t)(tile0 + r) * CO + sch) = v;
        }
    }
}

extern "C" void kernel_launch(void* const* d_in, const int* in_sizes, int n_in,
                              void* d_out, int out_size, void* d_ws, size_t ws_size,
                              hipStream_t stream)
{
    const float* X  = (const float*)d_in[0];
    const float* P  = (const float*)d_in[1];
    const float* Wk = (const float*)d_in[2];
    float* out = (float*)d_out;
    __bf16* wsF = (__bf16*)d_ws;   // 1024*64*2 = 128 KB

    wk_pack_kernel<<<dim3(QDIM / 32), dim3(256), 0, stream>>>(Wk, wsF);
    cond_dense_kernel<<<dim3(NBLK), dim3(WG_THREADS), 0, stream>>>(X, P, wsF, out);
}